// Round 2
// baseline (461.541 us; speedup 1.0000x reference)
//
#include <hip/hip_runtime.h>
#include <stdint.h>
#include <math.h>

#define SEQ 2048
#define NH 16
#define DM 1024

typedef __bf16 bf16x8 __attribute__((ext_vector_type(8)));
typedef float f32x4 __attribute__((ext_vector_type(4)));

__device__ __forceinline__ unsigned short f2bf(float f) {
  union { float f; unsigned u; } v; v.f = f;
  unsigned r = v.u + 0x7fffu + ((v.u >> 16) & 1u);
  return (unsigned short)(r >> 16);
}

__device__ __forceinline__ void load_lds16(const void* g, void* l) {
  __builtin_amdgcn_global_load_lds((__attribute__((address_space(1))) void*)g,
                                   (__attribute__((address_space(3))) void*)l,
                                   16, 0, 0);
}

// ---------------------------------------------------------------------------
// fp32 -> bf16 conversion for x (4M elems) + wq/wk/wv/wo (1M each), into ws.
// 2M threads x 4 elems.
// ---------------------------------------------------------------------------
__global__ void cvt_all(const float* __restrict__ x, const float* __restrict__ wq,
                        const float* __restrict__ wk, const float* __restrict__ wv,
                        const float* __restrict__ wo, unsigned short* __restrict__ ws) {
  const int i = blockIdx.x * blockDim.x + threadIdx.x;
  const int off = i * 4;
  const float* src;
  unsigned short* dst;
  if (off < 4194304) {
    src = x + off;
    dst = ws + off;
  } else {
    const int r = off - 4194304;
    const int w = r >> 20;
    const int o = r & 1048575;
    const float* tabs[4] = {wq, wk, wv, wo};
    src = tabs[w] + o;
    dst = ws + 4194304 + (w << 20) + o;
  }
  const float4 v = *(const float4*)src;
  ushort4 u;
  u.x = f2bf(v.x); u.y = f2bf(v.y); u.z = f2bf(v.z); u.w = f2bf(v.w);
  *(ushort4*)dst = u;
}

// ---------------------------------------------------------------------------
// gemm_bt: C = A (MxK row-major, bf16) * B^T (B is NxK row-major, bf16). K=1024.
// 128x128 tile, BK=32, 256 threads = 4 waves in 2x2, each wave 64x64 (4x4 MFMA).
// MODE 0/1: A=x, B=wq/wk -> RoPE -> Qr/Kr bf16 in (b,h,s,d)
// MODE 2:   A=wv, B=x    -> Vt bf16 in (b,h,d,s)
// MODE 3:   A=attn, B=wo -> out (b,s,dm) fp32
// ---------------------------------------------------------------------------
template <int MODE>
__launch_bounds__(256, 2)
__global__ void gemm_bt_kernel(const unsigned short* __restrict__ A,
                               const unsigned short* __restrict__ B,
                               void* __restrict__ Cout,
                               const int* __restrict__ tp) {
  __shared__ __align__(16) char smem[16384];
  char* As = smem;          // 128 x 32 bf16, row stride 64B
  char* Bs = smem + 8192;   // 128 x 32 bf16 (rows = n of B^T)

  const int t = threadIdx.x;
  const int lane = t & 63, wave = t >> 6;
  const int quad = lane >> 4, l16 = lane & 15;
  const int m0 = blockIdx.y * 128, n0 = blockIdx.x * 128;
  const int wm = (wave >> 1) * 64, wn = (wave & 1) * 64;

  f32x4 acc[4][4];
#pragma unroll
  for (int i = 0; i < 4; i++)
#pragma unroll
    for (int j = 0; j < 4; j++) {
      acc[i][j][0] = 0.f; acc[i][j][1] = 0.f; acc[i][j][2] = 0.f; acc[i][j][3] = 0.f;
    }

  const int rr = t >> 2;          // 0..63 row within 64-row chunk
  const int cc = (t & 3) * 8;     // k element offset

  for (int k0 = 0; k0 < 1024; k0 += 32) {
    __syncthreads();
#pragma unroll
    for (int i = 0; i < 2; i++) {
      load_lds16(A + (uint64_t)(m0 + i * 64 + rr) * 1024 + k0 + cc,
                 As + i * 4096 + wave * 1024);
      load_lds16(B + (uint64_t)(n0 + i * 64 + rr) * 1024 + k0 + cc,
                 Bs + i * 4096 + wave * 1024);
    }
    __syncthreads();

    bf16x8 af[4], bfr[4];
#pragma unroll
    for (int i = 0; i < 4; i++) {
      af[i]  = *(const bf16x8*)(As + (wm + i * 16 + l16) * 64 + quad * 16);
      bfr[i] = *(const bf16x8*)(Bs + (wn + i * 16 + l16) * 64 + quad * 16);
    }
#pragma unroll
    for (int i = 0; i < 4; i++)
#pragma unroll
      for (int j = 0; j < 4; j++)
        acc[i][j] = __builtin_amdgcn_mfma_f32_16x16x32_bf16(af[i], bfr[j], acc[i][j], 0, 0, 0);
  }

  // epilogue. C/D layout: col = lane&15, row = quad*4 + reg  [m89/m91 verified]
#pragma unroll
  for (int i = 0; i < 4; i++) {
#pragma unroll
    for (int j = 0; j < 4; j++) {
#pragma unroll
      for (int r = 0; r < 4; r++) {
        const int m = m0 + wm + i * 16 + quad * 4 + r;
        const int n = n0 + wn + j * 16 + l16;
        float v = acc[i][j][r];
        if (MODE == 0 || MODE == 1) {
          // m = (b,s), n = (h,d); RoPE interleaved pairs, partner in lane^1
          float p = __shfl_xor(v, 1);
          const int s = m & 2047, b = m >> 11;
          const int h = n >> 6, d = n & 63;
          const int pos = tp[(b << 11) + s];
          // inv_freq = 10000^(-(d&~1)/64) = 2^(-log2(1e4)/64 * (d&~1))
          float freq = exp2f(-0.20762050594f * (float)(d & ~1));
          float sn, cs;
          sincosf((float)pos * freq, &sn, &cs);  // accurate: v_sin is range-limited
          float rv = (n & 1) ? (p * sn + v * cs) : (v * cs - p * sn);
          ((unsigned short*)Cout)[((uint64_t)((b * NH + h) * SEQ + s)) * 64 + d] = f2bf(rv);
        } else if (MODE == 2) {
          // m = (h,d) of wv rows, n = (b,s) of x rows -> Vt[b][h][d][s]
          const int h = m >> 6, d = m & 63;
          const int b = n >> 11, s = n & 2047;
          ((unsigned short*)Cout)[((uint64_t)((b * NH + h) * 64 + d)) * SEQ + s] = f2bf(v);
        } else {
          ((float*)Cout)[(uint64_t)m * DM + n] = v;
        }
      }
    }
  }
}

// ---------------------------------------------------------------------------
// flash attention: one block per (q-tile of 64, b*h). 256 threads = 4 waves,
// each wave one 16-row Q strip. K/V tiles of 64 keys staged in LDS.
// Q,K in (b,h,s,64); Vt in (b,h,64,s); out At in (b,s,h,64) bf16.
// ---------------------------------------------------------------------------
__launch_bounds__(256, 2)
__global__ void flash_attn(const unsigned short* __restrict__ Q,
                           const unsigned short* __restrict__ K,
                           const unsigned short* __restrict__ Vt,
                           unsigned short* __restrict__ Oa) {
  __shared__ __align__(16) char smem[24576];
  char* Ks = smem;           // 64 keys x 64 d, row stride 128B
  char* Vs = smem + 8192;    // 64 d   x 64 keys, row stride 128B
  char* Ps = smem + 16384;   // 4 waves x (16 q x 64 keys)

  const int t = threadIdx.x;
  const int lane = t & 63, wave = t >> 6;
  const int quad = lane >> 4, l16 = lane & 15;
  const int qt = blockIdx.x, bh = blockIdx.y;
  const int qbase = qt * 64;
  const uint64_t base = (uint64_t)bh * SEQ * 64;  // same plane stride for Q,K,Vt

  // Q fragments (A-operand layout: m=lane&15, k=quad*8+j), held in regs
  bf16x8 qf[2];
  {
    const unsigned short* qp = Q + base + (uint64_t)(qbase + wave * 16 + l16) * 64 + quad * 8;
    qf[0] = *(const bf16x8*)qp;
    qf[1] = *(const bf16x8*)(qp + 32);
  }

  f32x4 o[4];
  float mI[4], lI[4];
#pragma unroll
  for (int i = 0; i < 4; i++) {
    o[i][0] = 0.f; o[i][1] = 0.f; o[i][2] = 0.f; o[i][3] = 0.f;
    mI[i] = -1e30f; lI[i] = 0.f;
  }
  const int qrow = qbase + wave * 16 + quad * 4;  // + r

  const int rr = t >> 3;        // 0..31 row within 32-row staging chunk
  const int cc = (t & 7) * 8;   // col element offset

  for (int kt = 0; kt <= qt; kt++) {
    const int kb = kt * 64;
    __syncthreads();
#pragma unroll
    for (int i = 0; i < 2; i++) {
      load_lds16(K + base + (uint64_t)(kb + i * 32 + rr) * 64 + cc,
                 Ks + i * 4096 + wave * 1024);
      load_lds16(Vt + base + (uint64_t)(i * 32 + rr) * SEQ + kb + cc,
                 Vs + i * 4096 + wave * 1024);
    }
    __syncthreads();

    // scores S = Q K^T * 1/8  (per wave: 16 q x 64 keys)
    f32x4 sf[4];
#pragma unroll
    for (int nb = 0; nb < 4; nb++) {
      f32x4 s; s[0] = 0.f; s[1] = 0.f; s[2] = 0.f; s[3] = 0.f;
#pragma unroll
      for (int kk = 0; kk < 2; kk++) {
        bf16x8 bfr = *(const bf16x8*)(Ks + (nb * 16 + l16) * 128 + kk * 64 + quad * 16);
        s = __builtin_amdgcn_mfma_f32_16x16x32_bf16(qf[kk], bfr, s, 0, 0, 0);
      }
      sf[nb] = s * 0.125f;
    }
    if (kt == qt) {  // diagonal tile: causal mask
#pragma unroll
      for (int nb = 0; nb < 4; nb++)
#pragma unroll
        for (int r = 0; r < 4; r++)
          if (kb + nb * 16 + l16 > qrow + r) sf[nb][r] = -1e30f;
    }

    // online softmax per q-row (row data lives in one 16-lane group)
#pragma unroll
    for (int r = 0; r < 4; r++) {
      float mx = fmaxf(fmaxf(sf[0][r], sf[1][r]), fmaxf(sf[2][r], sf[3][r]));
      mx = fmaxf(mx, __shfl_xor(mx, 1));
      mx = fmaxf(mx, __shfl_xor(mx, 2));
      mx = fmaxf(mx, __shfl_xor(mx, 4));
      mx = fmaxf(mx, __shfl_xor(mx, 8));
      float mnew = fmaxf(mI[r], mx);
      float alpha = __expf(mI[r] - mnew);
      mI[r] = mnew;
      float s0 = 0.f;
#pragma unroll
      for (int nb = 0; nb < 4; nb++) {
        float p = __expf(sf[nb][r] - mnew);
        sf[nb][r] = p;
        s0 += p;
      }
      s0 += __shfl_xor(s0, 1);
      s0 += __shfl_xor(s0, 2);
      s0 += __shfl_xor(s0, 4);
      s0 += __shfl_xor(s0, 8);
      lI[r] = lI[r] * alpha + s0;
#pragma unroll
      for (int db = 0; db < 4; db++) o[db][r] *= alpha;
    }

    // P (C-layout) -> LDS -> A-layout (per-wave private region)
    unsigned short* pw = (unsigned short*)(Ps + wave * 2048);
#pragma unroll
    for (int nb = 0; nb < 4; nb++)
#pragma unroll
      for (int r = 0; r < 4; r++)
        pw[(quad * 4 + r) * 64 + nb * 16 + l16] = f2bf(sf[nb][r]);
    __syncthreads();

#pragma unroll
    for (int kk = 0; kk < 2; kk++) {
      bf16x8 afr = *(const bf16x8*)(Ps + wave * 2048 + l16 * 128 + kk * 64 + quad * 16);
#pragma unroll
      for (int db = 0; db < 4; db++) {
        bf16x8 bfr = *(const bf16x8*)(Vs + (db * 16 + l16) * 128 + kk * 64 + quad * 16);
        o[db] = __builtin_amdgcn_mfma_f32_16x16x32_bf16(afr, bfr, o[db], 0, 0, 0);
      }
    }
  }

  // epilogue: write At (b, s, h, d) bf16
  const int b = bh >> 4, h = bh & 15;
  float invl[4];
#pragma unroll
  for (int r = 0; r < 4; r++) invl[r] = 1.0f / lI[r];
#pragma unroll
  for (int db = 0; db < 4; db++)
#pragma unroll
    for (int r = 0; r < 4; r++) {
      float v = o[db][r] * invl[r];
      Oa[((uint64_t)(b * SEQ + qrow + r)) * DM + h * 64 + db * 16 + l16] = f2bf(v);
    }
}

extern "C" void kernel_launch(void* const* d_in, const int* in_sizes, int n_in,
                              void* d_out, int out_size, void* d_ws, size_t ws_size,
                              hipStream_t stream) {
  const float* x  = (const float*)d_in[0];
  const int* tp   = (const int*)d_in[1];
  const float* wq = (const float*)d_in[2];
  const float* wk = (const float*)d_in[3];
  const float* wv = (const float*)d_in[4];
  const float* wo = (const float*)d_in[5];
  float* out = (float*)d_out;

  unsigned short* ws = (unsigned short*)d_ws;
  unsigned short* xb  = ws;                   // (b,s,dm) bf16   8 MB
  unsigned short* wqb = ws + 4194304;         // 2 MB
  unsigned short* wkb = ws + 5242880;
  unsigned short* wvb = ws + 6291456;
  unsigned short* wob = ws + 7340032;
  unsigned short* Qr  = ws + 8388608;         // (b,h,s,64)  8 MB
  unsigned short* Kr  = ws + 12582912;        // (b,h,s,64)  8 MB
  unsigned short* Vt  = ws + 16777216;        // (b,h,64,s)  8 MB
  unsigned short* At  = ws + 20971520;        // (b,s,h*64)  8 MB

  cvt_all<<<8192, 256, 0, stream>>>(x, wq, wk, wv, wo, ws);
  gemm_bt_kernel<0><<<dim3(8, 32), 256, 0, stream>>>(xb, wqb, Qr, tp);
  gemm_bt_kernel<1><<<dim3(8, 32), 256, 0, stream>>>(xb, wkb, Kr, tp);
  gemm_bt_kernel<2><<<dim3(32, 8), 256, 0, stream>>>(wvb, xb, Vt, nullptr);
  flash_attn<<<dim3(32, 32), 256, 0, stream>>>(Qr, Kr, Vt, At);
  gemm_bt_kernel<3><<<dim3(8, 32), 256, 0, stream>>>(At, wob, out, nullptr);
}

// Round 3
// 206.452 us; speedup vs baseline: 2.2356x; 2.2356x over previous
//
#include <hip/hip_runtime.h>
#include <stdint.h>
#include <math.h>

#define SEQ 2048
#define NH 16
#define DM 1024

typedef __bf16 bf16x8 __attribute__((ext_vector_type(8)));
typedef float f32x4 __attribute__((ext_vector_type(4)));

__device__ __forceinline__ unsigned short f2bf(float f) {
  union { float f; unsigned u; } v; v.f = f;
  unsigned r = v.u + 0x7fffu + ((v.u >> 16) & 1u);
  return (unsigned short)(r >> 16);
}
__device__ __forceinline__ unsigned pk2(float a, float b) {
  return (unsigned)f2bf(a) | ((unsigned)f2bf(b) << 16);
}
__device__ __forceinline__ void load_lds16(const void* g, void* l) {
  __builtin_amdgcn_global_load_lds((__attribute__((address_space(1))) void*)g,
                                   (__attribute__((address_space(3))) void*)l,
                                   16, 0, 0);
}

// ---------------------------------------------------------------------------
// fp32 -> bf16 conversion: x (4M) + wq/wk/wv/wo (1M each) into ws.
// ---------------------------------------------------------------------------
__global__ void cvt_all(const float* __restrict__ x, const float* __restrict__ wq,
                        const float* __restrict__ wk, const float* __restrict__ wv,
                        const float* __restrict__ wo, unsigned short* __restrict__ ws) {
  const int i = blockIdx.x * blockDim.x + threadIdx.x;
  const int off = i * 4;
  const float* src;
  unsigned short* dst;
  if (off < 4194304) {
    src = x + off;  dst = ws + off;
  } else {
    const int r = off - 4194304;
    const int w = r >> 20, o = r & 1048575;
    const float* tabs[4] = {wq, wk, wv, wo};
    src = tabs[w] + o;  dst = ws + 4194304 + (w << 20) + o;
  }
  const float4 v = *(const float4*)src;
  ushort4 u;
  u.x = f2bf(v.x); u.y = f2bf(v.y); u.z = f2bf(v.z); u.w = f2bf(v.w);
  *(ushort4*)dst = u;
}

// ---------------------------------------------------------------------------
// Fused QKV projection: C = x (4096x1024) @ W3^T (W3 = [wq;wk;wv], 3072x1024).
// 128x128 tiles, grid (24, 32) = 768 blocks (3/CU).
// n in [0,1024): RoPE -> Qr (b,h,s,d); [1024,2048): RoPE -> Kr; else Vt (b,h,d,s).
// ---------------------------------------------------------------------------
__launch_bounds__(256, 2)
__global__ void gemm_qkv(const unsigned short* __restrict__ X,
                         const unsigned short* __restrict__ W3,
                         unsigned short* __restrict__ Qr,
                         unsigned short* __restrict__ Kr,
                         unsigned short* __restrict__ Vt,
                         const int* __restrict__ tp) {
  __shared__ __align__(16) char smem[16384];
  char* As = smem;
  char* Bs = smem + 8192;

  const int t = threadIdx.x;
  const int lane = t & 63, wave = t >> 6;
  const int quad = lane >> 4, l16 = lane & 15;
  const int m0 = blockIdx.y * 128, n0 = blockIdx.x * 128;
  const int wm = (wave >> 1) * 64, wn = (wave & 1) * 64;

  f32x4 acc[4][4];
#pragma unroll
  for (int i = 0; i < 4; i++)
#pragma unroll
    for (int j = 0; j < 4; j++) { acc[i][j][0]=0.f; acc[i][j][1]=0.f; acc[i][j][2]=0.f; acc[i][j][3]=0.f; }

  const int rr = t >> 2;
  const int cc = (t & 3) * 8;

  for (int k0 = 0; k0 < 1024; k0 += 32) {
    __syncthreads();
#pragma unroll
    for (int i = 0; i < 2; i++) {
      load_lds16(X  + (uint64_t)(m0 + i * 64 + rr) * 1024 + k0 + cc, As + i * 4096 + wave * 1024);
      load_lds16(W3 + (uint64_t)(n0 + i * 64 + rr) * 1024 + k0 + cc, Bs + i * 4096 + wave * 1024);
    }
    __syncthreads();

    bf16x8 af[4], bfr[4];
#pragma unroll
    for (int i = 0; i < 4; i++) {
      af[i]  = *(const bf16x8*)(As + (wm + i * 16 + l16) * 64 + quad * 16);
      bfr[i] = *(const bf16x8*)(Bs + (wn + i * 16 + l16) * 64 + quad * 16);
    }
#pragma unroll
    for (int i = 0; i < 4; i++)
#pragma unroll
      for (int j = 0; j < 4; j++)
        acc[i][j] = __builtin_amdgcn_mfma_f32_16x16x32_bf16(af[i], bfr[j], acc[i][j], 0, 0, 0);
  }

  if (n0 < 2048) {
    // Q or K with RoPE. n = n0+wn+j*16+l16; d = n&63; pairs via lane^1.
    unsigned short* dst = (n0 < 1024) ? Qr : Kr;
    float fr[4]; int dd[4], hh[4];
#pragma unroll
    for (int j = 0; j < 4; j++) {
      const int n = n0 + wn + j * 16 + l16;
      dd[j] = n & 63;
      hh[j] = (n & 1023) >> 6;
      // 10000^(-(d&~1)/64) / (2*pi), computed as exp2
      fr[j] = __builtin_amdgcn_exp2f(-0.20762050594f * (float)(dd[j] & ~1)) * 0.15915494309f;
    }
    const float sgnodd = (l16 & 1) ? 1.f : -1.f;
#pragma unroll
    for (int i = 0; i < 4; i++) {
#pragma unroll
      for (int r = 0; r < 4; r++) {
        const int m = m0 + wm + i * 16 + quad * 4 + r;
        const int s = m & 2047, b = m >> 11;
        const float posf = (float)tp[m];
#pragma unroll
        for (int j = 0; j < 4; j++) {
          const float v = acc[i][j][r];
          const float p = __shfl_xor(v, 1);
          float rev = posf * fr[j];
          rev -= floorf(rev);
          float sn, cs;
          asm("v_sin_f32 %0, %1" : "=v"(sn) : "v"(rev));
          asm("v_cos_f32 %0, %1" : "=v"(cs) : "v"(rev));
          const float rv = fmaf(v, cs, p * sn * sgnodd);
          dst[((uint64_t)((b * NH + hh[j]) * SEQ + s)) * 64 + dd[j]] = f2bf(rv);
        }
      }
    }
  } else {
    // V -> Vt (b,h,d,s), pack 4 consecutive s as one 8B store
#pragma unroll
    for (int i = 0; i < 4; i++) {
      const int m = m0 + wm + i * 16 + quad * 4;
      const int s = m & 2047, b = m >> 11;
#pragma unroll
      for (int j = 0; j < 4; j++) {
        const int n = n0 - 2048 + wn + j * 16 + l16;
        const int h = n >> 6, d = n & 63;
        uint2 w;
        w.x = pk2(acc[i][j][0], acc[i][j][1]);
        w.y = pk2(acc[i][j][2], acc[i][j][3]);
        *(uint2*)(Vt + ((uint64_t)((b * NH + h) * 64 + d)) * SEQ + s) = w;
      }
    }
  }
}

// ---------------------------------------------------------------------------
// Output projection: C = At (4096x1024) @ wo^T, fp32 out. 128x64 tiles,
// grid (16, 32) = 512 blocks (2/CU). 4 waves 2x2, wave = 64m x 32n.
// ---------------------------------------------------------------------------
__launch_bounds__(256, 2)
__global__ void gemm_ao(const unsigned short* __restrict__ A,
                        const unsigned short* __restrict__ B,
                        float* __restrict__ C) {
  __shared__ __align__(16) char smem[12288];
  char* As = smem;          // 128 x 32
  char* Bs = smem + 8192;   // 64 x 32

  const int t = threadIdx.x;
  const int lane = t & 63, wave = t >> 6;
  const int quad = lane >> 4, l16 = lane & 15;
  const int m0 = blockIdx.y * 128, n0 = blockIdx.x * 64;
  const int wm = (wave >> 1) * 64, wn = (wave & 1) * 32;

  f32x4 acc[4][2];
#pragma unroll
  for (int i = 0; i < 4; i++)
#pragma unroll
    for (int j = 0; j < 2; j++) { acc[i][j][0]=0.f; acc[i][j][1]=0.f; acc[i][j][2]=0.f; acc[i][j][3]=0.f; }

  const int rr = t >> 2;
  const int cc = (t & 3) * 8;

  for (int k0 = 0; k0 < 1024; k0 += 32) {
    __syncthreads();
#pragma unroll
    for (int i = 0; i < 2; i++)
      load_lds16(A + (uint64_t)(m0 + i * 64 + rr) * 1024 + k0 + cc, As + i * 4096 + wave * 1024);
    load_lds16(B + (uint64_t)(n0 + rr) * 1024 + k0 + cc, Bs + wave * 1024);
    __syncthreads();

    bf16x8 af[4], bfr[2];
#pragma unroll
    for (int i = 0; i < 4; i++)
      af[i] = *(const bf16x8*)(As + (wm + i * 16 + l16) * 64 + quad * 16);
#pragma unroll
    for (int j = 0; j < 2; j++)
      bfr[j] = *(const bf16x8*)(Bs + (wn + j * 16 + l16) * 64 + quad * 16);
#pragma unroll
    for (int i = 0; i < 4; i++)
#pragma unroll
      for (int j = 0; j < 2; j++)
        acc[i][j] = __builtin_amdgcn_mfma_f32_16x16x32_bf16(af[i], bfr[j], acc[i][j], 0, 0, 0);
  }

#pragma unroll
  for (int i = 0; i < 4; i++)
#pragma unroll
    for (int j = 0; j < 2; j++)
#pragma unroll
      for (int r = 0; r < 4; r++) {
        const int m = m0 + wm + i * 16 + quad * 4 + r;
        const int n = n0 + wn + j * 16 + l16;
        C[(uint64_t)m * DM + n] = acc[i][j][r];
      }
}

// ---------------------------------------------------------------------------
// Flash attention, transposed scheme. Block = (64 q) x (b*h); 4 waves, wave
// owns 16 q (q = l16). S^T = K Q^T per 64-key tile -> softmax (q per lane) ->
// O^T += V^T P^T. XOR-swizzled LDS (conflict-free b128), double-buffered K/V
// staging, 1 barrier/iter. Out At (b,s,h,d) bf16.
// ---------------------------------------------------------------------------
__launch_bounds__(256, 4)
__global__ void flash_attn(const unsigned short* __restrict__ Q,
                           const unsigned short* __restrict__ K,
                           const unsigned short* __restrict__ Vt,
                           unsigned short* __restrict__ Oa) {
  __shared__ __align__(16) char smem[40960];
  // Ks buf b: smem + b*8192          (64 key-rows x 128B, chunks swizzled)
  // Vs buf b: smem + 16384 + b*8192  (64 d-rows   x 128B, chunks swizzled)
  // Ps      : smem + 32768 + wave*2048 (16 q-rows x 128B, chunks swizzled)

  const int t = threadIdx.x;
  const int lane = t & 63, wave = t >> 6;
  const int quad = lane >> 4, l16 = lane & 15;
  const int bx = blockIdx.x;
  const int qt = (bx & 1) ? (31 - (bx >> 1)) : (bx >> 1);  // pair long+short
  const int bh = blockIdx.y;
  const int qbase = qt * 64;
  const uint64_t base = (uint64_t)bh * (SEQ * 64);
  const int qg = qbase + wave * 16 + l16;  // this lane's q row

  // Q B-fragment: lane n=q=l16, k=d=kk*32+quad*8+j
  bf16x8 qf[2];
  {
    const unsigned short* qp = Q + base + (uint64_t)qg * 64 + quad * 8;
    qf[0] = *(const bf16x8*)qp;
    qf[1] = *(const bf16x8*)(qp + 32);
  }

  f32x4 o[4];
#pragma unroll
  for (int i = 0; i < 4; i++) { o[i][0]=0.f; o[i][1]=0.f; o[i][2]=0.f; o[i][3]=0.f; }
  float mI = -1e30f, lI = 0.f;

  const int srow = wave * 8 + (lane >> 3);             // staging row (+i*32)
  const int sc = ((lane & 7) ^ (lane >> 3)) * 8;       // swizzled chunk, shorts
  const int swz = (l16 & 7);                           // frag-read swizzle key
  char* ps = smem + 32768 + wave * 2048;

#define STAGE(bufidx, kb_) do {                                                   \
    char* kd_ = smem + (bufidx) * 8192;                                           \
    char* vd_ = smem + 16384 + (bufidx) * 8192;                                   \
    _Pragma("unroll")                                                             \
    for (int i_ = 0; i_ < 2; i_++) {                                              \
      load_lds16(K  + base + (uint64_t)((kb_) + i_ * 32 + srow) * 64 + sc,        \
                 kd_ + i_ * 4096 + wave * 1024);                                  \
      load_lds16(Vt + base + (uint64_t)(i_ * 32 + srow) * SEQ + (kb_) + sc,       \
                 vd_ + i_ * 4096 + wave * 1024);                                  \
    }                                                                             \
  } while (0)

  STAGE(0, 0);

  for (int kt = 0; kt <= qt; kt++) {
    const int kb = kt * 64;
    const int buf = kt & 1;
    __syncthreads();               // staging of buf done; prev reads of buf^1 done
    if (kt < qt) STAGE(buf ^ 1, kb + 64);
    char* ks = smem + buf * 8192;
    char* vs = smem + 16384 + buf * 8192;
    const bool diag = (kt == qt);
    const int nbmax = diag ? (wave + 1) : 4;

    // S^T = K Q^T : A=K-frag (m=key), B=Q-frag (n=q). C: key=quad*4+r, q=l16.
    f32x4 sf[4];
#pragma unroll
    for (int nb = 0; nb < 4; nb++) {
      if (nb < nbmax) {
        f32x4 s; s[0]=0.f; s[1]=0.f; s[2]=0.f; s[3]=0.f;
#pragma unroll
        for (int kk = 0; kk < 2; kk++) {
          bf16x8 kfr = *(const bf16x8*)(ks + (nb * 16 + l16) * 128 + (((kk * 4 + quad) ^ swz) * 16));
          s = __builtin_amdgcn_mfma_f32_16x16x32_bf16(kfr, qf[kk], s, 0, 0, 0);
        }
        sf[nb] = s;
      } else {
        sf[nb][0] = -1e30f; sf[nb][1] = -1e30f; sf[nb][2] = -1e30f; sf[nb][3] = -1e30f;
      }
    }
    if (diag) {
#pragma unroll
      for (int nb = 0; nb < 4; nb++)
#pragma unroll
        for (int r = 0; r < 4; r++)
          if (kb + nb * 16 + quad * 4 + r > qg) sf[nb][r] = -1e30f;
    }

    // online softmax; q lives in lane (l16), key-partials across quads
    float mx = sf[0][0];
#pragma unroll
    for (int nb = 0; nb < 4; nb++)
#pragma unroll
      for (int r = 0; r < 4; r++) mx = fmaxf(mx, sf[nb][r]);
    mx = fmaxf(mx, __shfl_xor(mx, 16));
    mx = fmaxf(mx, __shfl_xor(mx, 32));
    const float mnew = fmaxf(mI, mx);
    const float c1 = 0.18033688011f;  // log2(e)/8
    const float mc = mnew * c1;
    const float alpha = __builtin_amdgcn_exp2f(mI * c1 - mc);
    mI = mnew;
    float ls = 0.f;
#pragma unroll
    for (int nb = 0; nb < 4; nb++)
#pragma unroll
      for (int r = 0; r < 4; r++) {
        const float p = __builtin_amdgcn_exp2f(sf[nb][r] * c1 - mc);
        sf[nb][r] = p;
        ls += p;
      }
    lI = lI * alpha + ls;   // lane-local partial (this quad's keys); reduced at end
#pragma unroll
    for (int db = 0; db < 4; db++)
#pragma unroll
      for (int r = 0; r < 4; r++) o[db][r] *= alpha;

    // P^T -> Ps (row=q(l16), 64 keys, swizzled chunks); vectorized b64 writes
#pragma unroll
    for (int nb = 0; nb < 4; nb++) {
      uint2 pv;
      pv.x = pk2(sf[nb][0], sf[nb][1]);
      pv.y = pk2(sf[nb][2], sf[nb][3]);
      *(uint2*)(ps + l16 * 128 + (((nb * 2 + (quad >> 1)) ^ swz) * 16) + (quad & 1) * 8) = pv;
    }
    // wave-private region: compiler's lgkmcnt ordering suffices, no barrier.

    // O^T += V^T P^T : A=V-frag (m=d), B=P-frag (n=q)
    const int kkmax = diag ? ((wave >> 1) + 1) : 2;
    for (int kk = 0; kk < kkmax; kk++) {
      bf16x8 pf = *(const bf16x8*)(ps + l16 * 128 + (((kk * 4 + quad) ^ swz) * 16));
#pragma unroll
      for (int db = 0; db < 4; db++) {
        bf16x8 vf = *(const bf16x8*)(vs + (db * 16 + l16) * 128 + (((kk * 4 + quad) ^ swz) * 16));
        o[db] = __builtin_amdgcn_mfma_f32_16x16x32_bf16(vf, pf, o[db], 0, 0, 0);
      }
    }
  }
#undef STAGE

  // final l reduction across quads, normalize, store At (b,s,h,d)
  lI += __shfl_xor(lI, 16);
  lI += __shfl_xor(lI, 32);
  const float invl = 1.0f / lI;
  const int b = bh >> 4, h = bh & 15;
  unsigned short* orow = Oa + ((uint64_t)(b * SEQ + qg)) * DM + h * 64 + quad * 4;
#pragma unroll
  for (int db = 0; db < 4; db++) {
    uint2 w;
    w.x = pk2(o[db][0] * invl, o[db][1] * invl);
    w.y = pk2(o[db][2] * invl, o[db][3] * invl);
    *(uint2*)(orow + db * 16) = w;
  }
}

extern "C" void kernel_launch(void* const* d_in, const int* in_sizes, int n_in,
                              void* d_out, int out_size, void* d_ws, size_t ws_size,
                              hipStream_t stream) {
  const float* x  = (const float*)d_in[0];
  const int* tp   = (const int*)d_in[1];
  const float* wq = (const float*)d_in[2];
  const float* wk = (const float*)d_in[3];
  const float* wv = (const float*)d_in[4];
  const float* wo = (const float*)d_in[5];
  float* out = (float*)d_out;

  unsigned short* ws = (unsigned short*)d_ws;
  unsigned short* xb  = ws;                   // (b,s,dm) bf16       8 MB
  unsigned short* w3b = ws + 4194304;         // [wq;wk;wv] 3072x1024 6 MB
  unsigned short* wob = ws + 7340032;         // 2 MB
  unsigned short* Qr  = ws + 8388608;         // (b,h,s,64)  8 MB
  unsigned short* Kr  = ws + 12582912;        // (b,h,s,64)  8 MB
  unsigned short* Vt  = ws + 16777216;        // (b,h,64,s)  8 MB
  unsigned short* At  = ws + 20971520;        // (b,s,h*64)  8 MB

  cvt_all<<<8192, 256, 0, stream>>>(x, wq, wk, wv, wo, ws);
  gemm_qkv<<<dim3(24, 32), 256, 0, stream>>>(xb, w3b, Qr, Kr, Vt, tp);
  flash_attn<<<dim3(32, 32), 256, 0, stream>>>(Qr, Kr, Vt, At);
  gemm_ao<<<dim3(16, 32), 256, 0, stream>>>(At, wob, out);
}